// Round 13
// baseline (327.676 us; speedup 1.0000x reference)
//
#include <hip/hip_runtime.h>
#include <hip/hip_fp16.h>
#include <stdint.h>

typedef _Float16 half8 __attribute__((ext_vector_type(8)));
typedef _Float16 half4v __attribute__((ext_vector_type(4)));
typedef float floatx4 __attribute__((ext_vector_type(4)));

// ---------------------------------------------------------------------------
// async global->LDS copy, 16B per lane. LDS dest = wave-uniform base + lane*16.
__device__ inline void gload_lds16(const void* g, void* l) {
    __builtin_amdgcn_global_load_lds(
        (const __attribute__((address_space(1))) uint32_t*)g,
        (__attribute__((address_space(3))) uint32_t*)l, 16, 0, 0);
}

// ---------------------------------------------------------------------------
// Pair split-cast: inA -> A-style [hi|lo|hi] at outA, inB -> B-style
// [hi|hi|lo] at outB. Both [n_each] elements, row width nc, out stride 3*nc.
__global__ __launch_bounds__(256) void split_cast_pair(
    const float* __restrict__ inA, _Float16* __restrict__ outA,
    const float* __restrict__ inB, _Float16* __restrict__ outB,
    int nc, int n_each) {
    int i = (blockIdx.x * 256 + threadIdx.x) * 4;
    if (i >= 2 * n_each) return;
    const bool second = (i >= n_each);
    const int ii = second ? i - n_each : i;
    const float* src = (second ? inB : inA) + ii;
    _Float16* out = second ? outB : outA;
    float4 v = *(const float4*)src;
    int r = ii / nc, c = ii % nc;
    half4v hi, lo;
    hi[0] = (_Float16)v.x; lo[0] = (_Float16)(v.x - (float)hi[0]);
    hi[1] = (_Float16)v.y; lo[1] = (_Float16)(v.y - (float)hi[1]);
    hi[2] = (_Float16)v.z; lo[2] = (_Float16)(v.z - (float)hi[2]);
    hi[3] = (_Float16)v.w; lo[3] = (_Float16)(v.w - (float)hi[3]);
    size_t base = (size_t)r * 3 * nc;
    if (!second) {  // A-style
        *(half4v*)(out + base + c) = hi;
        *(half4v*)(out + base + nc + c) = lo;
        *(half4v*)(out + base + 2 * nc + c) = hi;
    } else {        // B-style
        *(half4v*)(out + base + c) = hi;
        *(half4v*)(out + base + nc + c) = hi;
        *(half4v*)(out + base + 2 * nc + c) = lo;
    }
}

// ---------------------------------------------------------------------------
// transpose + B-style split cat [hi | hi | lo]: out[n][...]=f(in[k][n]).
__global__ __launch_bounds__(256) void transpose_split_b(
    const float* __restrict__ in, _Float16* __restrict__ out, int dim) {
    __shared__ float tile[32][33];
    const int tx = threadIdx.x, ty = threadIdx.y;
    const int bx = blockIdx.x * 32, by = blockIdx.y * 32;
#pragma unroll
    for (int i = 0; i < 32; i += 8)
        tile[ty + i][tx] = in[(size_t)(by + ty + i) * dim + bx + tx];
    __syncthreads();
#pragma unroll
    for (int i = 0; i < 32; i += 8) {
        float v = tile[tx][ty + i];
        _Float16 hi = (_Float16)v;
        _Float16 lo = (_Float16)(v - (float)hi);
        size_t o = (size_t)(bx + ty + i) * 3 * dim + by + tx;
        out[o] = hi;
        out[o + dim] = hi;
        out[o + 2 * dim] = lo;
    }
}

// ---------------------------------------------------------------------------
// 128x128-tile, 512-thread / 8-wave (4M x 2N) GEMM: C = A @ B^T.
// Each wave owns a 32x64 sub-tile (acc 2x4) -> 2 waves/SIMD overlap.
template <int OMODE>
__global__ __launch_bounds__(512) void gemm_bt8(
    const _Float16* __restrict__ A, const _Float16* __restrict__ B,
    void* __restrict__ Cout, int M, int N, int K, int lda, int ldb,
    float cscale) {
    __shared__ _Float16 As[128 * 64];
    __shared__ _Float16 Bs[128 * 64];

    const int tid  = threadIdx.x;
    const int lane = tid & 63;
    const int wid  = tid >> 6;    // 0..7
    const int wr   = wid >> 1;    // 0..3  M-quarter (32 rows)
    const int wc   = wid & 1;     // 0..1  N-half (64 cols)
    const int row0 = blockIdx.y * 128;
    const int col0 = blockIdx.x * 128;

    floatx4 acc[2][4] = {};

    const int srow   = lane >> 3;
    const int schunk = (lane & 7) ^ srow;      // source-side XOR swizzle
    const char* gA = (const char*)(A + (size_t)(row0 + wid * 8 + srow) * lda) + schunk * 16;
    const char* gB = (const char*)(B + (size_t)(col0 + wid * 8 + srow) * ldb) + schunk * 16;
    char* lA = (char*)As + (wid * 8) * 128;
    char* lB = (char*)Bs + (wid * 8) * 128;

    const int frow   = lane & 15;
    const int rxor   = frow & 7;
    const int kchunk = lane >> 4;

    const int kTiles = K >> 6;
    for (int kt = 0; kt < kTiles; ++kt) {
        const size_t kb = (size_t)(kt << 6) * 2;
#pragma unroll
        for (int r = 0; r < 2; ++r) {
            gload_lds16(gA + (size_t)(r * 64) * lda * 2 + kb, lA + r * 64 * 128);
            gload_lds16(gB + (size_t)(r * 64) * ldb * 2 + kb, lB + r * 64 * 128);
        }
        __syncthreads();
#pragma unroll
        for (int kk = 0; kk < 2; ++kk) {
            half8 af[2], bf[4];
            const int pc = ((kk * 4 + kchunk) ^ rxor) * 16;
#pragma unroll
            for (int mi = 0; mi < 2; ++mi)
                af[mi] = *(const half8*)((const char*)As + (wr * 32 + mi * 16 + frow) * 128 + pc);
#pragma unroll
            for (int ni = 0; ni < 4; ++ni)
                bf[ni] = *(const half8*)((const char*)Bs + (wc * 64 + ni * 16 + frow) * 128 + pc);
#pragma unroll
            for (int mi = 0; mi < 2; ++mi)
#pragma unroll
                for (int ni = 0; ni < 4; ++ni)
                    acc[mi][ni] = __builtin_amdgcn_mfma_f32_16x16x32_f16(
                        af[mi], bf[ni], acc[mi][ni], 0, 0, 0);
        }
        __syncthreads();
    }

    // epilogue: D row = 4*(lane>>4)+j, col = lane&15
    const int orow0 = row0 + wr * 32 + ((lane >> 4) << 2);
    const int ocol0 = col0 + wc * 64 + (lane & 15);
#pragma unroll
    for (int mi = 0; mi < 2; ++mi) {
#pragma unroll
        for (int ni = 0; ni < 4; ++ni) {
#pragma unroll
            for (int j = 0; j < 4; ++j) {
                const int rr = orow0 + mi * 16 + j;
                const int cc = ocol0 + ni * 16;
                const float v = acc[mi][ni][j] * cscale;
                if (OMODE == 1) {
                    ((_Float16*)Cout)[(size_t)cc * M + rr] = (_Float16)v;
                } else if (OMODE == 3) {
                    ((float*)Cout)[(size_t)rr * N + cc] = v;
                } else {
                    _Float16 hi = (_Float16)v;
                    _Float16 lo = (_Float16)(v - (float)hi);
                    _Float16* o = (_Float16*)Cout + (size_t)rr * 3 * N + cc;
                    if (OMODE == 4) { o[0] = hi; o[N] = lo; o[2 * N] = hi; }
                    else            { o[0] = hi; o[N] = hi; o[2 * N] = lo; }
                }
            }
        }
    }
}

// ---------------------------------------------------------------------------
// 256x256-tile, BK=64, 8-wave (2Mx4N).  R12's spread staging + NEW: A-fragment
// cross-phase prefetch with COUNTED lgkmcnt (ag[] set, +16 VGPR):
//   P0 serial A(0,0)+B(0) LGK(0); issue A(0,1)->ag under MFMA(af).
//   P1 issue A(1,0)->af;  LGK(4) drains ag;        MFMA(ag).
//   P2 issue B(1)+A(1,1)->ag; LGK(4) drains af+bf; MFMA(af).
//   P3 stage-6 t+2; LGK(0) drains ag (in flight since P2); vmcnt(6); MFMA(ag).
// WAR safe: each set overwritten only after its MFMA issued (in-wave order);
// cross-wave: every drain precedes its phase's closing barrier.
#define SB0() __builtin_amdgcn_sched_barrier(0)
#define BAR() __builtin_amdgcn_s_barrier()

#define RD_A4(DST, KK, MH)                                                    \
    {                                                                         \
        const int pc_ = (((KK) * 4 + kchunk) ^ rxor) * 16;                    \
        _Pragma("unroll")                                                     \
        for (int mi = 0; mi < 4; ++mi)                                        \
            DST[mi] = *(const half8*)(bsA + (wr * 128 + ((MH) * 4 + mi) * 16 + frow) * 128 + pc_); \
    }

#define RD_B4(DST, KK)                                                        \
    {                                                                         \
        const int pc_ = (((KK) * 4 + kchunk) ^ rxor) * 16;                    \
        _Pragma("unroll")                                                     \
        for (int ni = 0; ni < 4; ++ni)                                        \
            DST[ni] = *(const half8*)(bsB + (wc * 64 + ni * 16 + frow) * 128 + pc_); \
    }

#define PH_MFMA(AF, MH)                                                       \
    __builtin_amdgcn_s_setprio(1);                                            \
    _Pragma("unroll")                                                         \
    for (int mi = 0; mi < 4; ++mi)                                            \
        _Pragma("unroll")                                                     \
        for (int ni = 0; ni < 4; ++ni)                                        \
            acc[(MH) * 4 + mi][ni] = __builtin_amdgcn_mfma_f32_16x16x32_f16(  \
                AF[mi], bf[ni], acc[(MH) * 4 + mi][ni], 0, 0, 0);             \
    __builtin_amdgcn_s_setprio(0);

#define STG_A(DST, tt, i)                                                     \
    gload_lds16(gA + (size_t)((i) * 64) * lda + (size_t)(tt) * 64,            \
                (char*)(DST) + (wid * 8 + (i) * 64) * 128);
#define STG_B(DST, tt, i)                                                     \
    gload_lds16(gB + (size_t)((i) * 64) * ldb + (size_t)(tt) * 64,            \
                (char*)(DST) + (wid * 8 + (i) * 64) * 128);

#define LGK(N) asm volatile("s_waitcnt lgkmcnt(" #N ")" ::: "memory")
#define VMC(N) asm volatile("s_waitcnt vmcnt(" #N ")" ::: "memory")

__global__ __launch_bounds__(512, 2) void gemm256_bt_f32(
    const _Float16* __restrict__ A, const _Float16* __restrict__ B,
    float* __restrict__ C, int M, int N, int K, int lda, int ldb,
    float cscale) {
    __shared__ _Float16 As[2][256 * 64];   // 2 x 32 KiB
    __shared__ _Float16 Bs[2][256 * 64];   // 2 x 32 KiB  (total 128 KiB)

    const int tid  = threadIdx.x;
    const int lane = tid & 63;
    const int wid  = tid >> 6;     // 0..7
    const int wr   = wid >> 2;     // 0..1  M-half
    const int wc   = wid & 3;      // 0..3  N-quarter
    const int row0 = blockIdx.y * 256;
    const int col0 = blockIdx.x * 256;

    floatx4 acc[8][4] = {};

    const int srow   = lane >> 3;
    const int schunk = (lane & 7) ^ srow;    // pre-swizzled global source
    const _Float16* gA = A + (size_t)(row0 + wid * 8 + srow) * lda + schunk * 8;
    const _Float16* gB = B + (size_t)(col0 + wid * 8 + srow) * ldb + schunk * 8;

    const int frow   = lane & 15;
    const int rxor   = frow & 7;
    const int kchunk = lane >> 4;

    const int NT = K >> 6;

    // prologue: stage tiles 0 and 1 fully; wait tile 0 (tile 1's 8 in flight)
#pragma unroll
    for (int i = 0; i < 4; ++i) { STG_A((char*)As[0], 0, i) STG_B((char*)Bs[0], 0, i) }
#pragma unroll
    for (int i = 0; i < 4; ++i) { STG_A((char*)As[1], 1, i) STG_B((char*)Bs[1], 1, i) }
    VMC(8);
    SB0();
    BAR();

    half8 af[4], ag[4], bf[4];
    for (int t = 0; t < NT; ++t) {
        const int d = t & 1;
        char* curA = (char*)As[0] + d * 32768;
        char* curB = (char*)Bs[0] + d * 32768;
        char* nxtA = (char*)As[0] + (d ^ 1) * 32768;
        const char* bsA = curA;
        const char* bsB = curB;

        // ---- P0: serial A(0,0)+B(0); finish staging t+1's A-MH1 into nxt
        RD_A4(af, 0, 0) RD_B4(bf, 0)
        if (t >= 1 && t + 1 < NT) { STG_A(nxtA, t + 1, 1) STG_A(nxtA, t + 1, 3) }
        SB0();
        BAR();
        LGK(0);
        SB0();
        RD_A4(ag, 0, 1)        // prefetch P1's A; flies under MFMA
        SB0();
        PH_MFMA(af, 0)
        BAR();

        // ---- P1: prefetch P2's A(1,0)->af; counted wait drains only ag
        RD_A4(af, 1, 0)
        SB0();
        BAR();
        LGK(4);                // outstanding ag(4)+af(4) -> drains ag
        SB0();
        PH_MFMA(ag, 1)
        BAR();

        // ---- P2: read B(1); prefetch P3's A(1,1)->ag; drain af+bf
        RD_B4(bf, 1)
        RD_A4(ag, 1, 1)
        SB0();
        BAR();
        LGK(4);                // outstanding af(4)+bf(4)+ag(4) -> drains af,bf
        SB0();
        PH_MFMA(af, 0)
        BAR();

        // ---- P3: stage 6 of t+2 into dead cur regions; drain ag; vmcnt(6)
        const bool pf = (t + 2 < NT);
        if (pf) {
            STG_B(curB, t + 2, 0) STG_B(curB, t + 2, 1)
            STG_B(curB, t + 2, 2) STG_B(curB, t + 2, 3)
            STG_A(curA, t + 2, 0) STG_A(curA, t + 2, 2)
        }
        SB0();
        BAR();
        LGK(0);                // drains ag (in flight since P2)
        SB0();
        if (pf) { VMC(6); } else { VMC(0); }
        SB0();
        PH_MFMA(ag, 1)
        BAR();                 // tile t+1 resident; cur A-MH1 now dead
    }

    // epilogue: D row = 4*(lane>>4)+j, col = lane&15
    const int orow0 = row0 + wr * 128 + ((lane >> 4) << 2);
    const int ocol0 = col0 + wc * 64 + frow;
#pragma unroll
    for (int mi = 0; mi < 8; ++mi) {
#pragma unroll
        for (int ni = 0; ni < 4; ++ni) {
#pragma unroll
            for (int j = 0; j < 4; ++j) {
                const int rr = orow0 + mi * 16 + j;
                const int cc = ocol0 + ni * 16;
                C[(size_t)rr * N + cc] = acc[mi][ni][j] * cscale;
            }
        }
    }
}

// ---------------------------------------------------------------------------
// row softmax over f32 S (already scaled /32), in place: writes normalized
// P = exp(s-m)/sum as f16 at the same row base (row stride ncols f32 slots).
__global__ __launch_bounds__(256) void softmax_inplace(
    float* __restrict__ S, int ncols) {
    const int row = blockIdx.x;
    float* srow = S + (size_t)row * ncols;
    const int t = threadIdx.x;

    float x[16];
#pragma unroll
    for (int q = 0; q < 4; ++q) {
        float4 v = *(float4*)(srow + t * 16 + q * 4);
        x[q * 4 + 0] = v.x; x[q * 4 + 1] = v.y;
        x[q * 4 + 2] = v.z; x[q * 4 + 3] = v.w;
    }
    float m = x[0];
#pragma unroll
    for (int j = 1; j < 16; ++j) m = fmaxf(m, x[j]);
#pragma unroll
    for (int off = 32; off; off >>= 1) m = fmaxf(m, __shfl_xor(m, off));
    __shared__ float redm[4];
    if ((t & 63) == 0) redm[t >> 6] = m;
    __syncthreads();
    m = fmaxf(fmaxf(redm[0], redm[1]), fmaxf(redm[2], redm[3]));

    float s = 0.0f;
#pragma unroll
    for (int j = 0; j < 16; ++j) {
        x[j] = __expf(x[j] - m);
        s += x[j];
    }
#pragma unroll
    for (int off = 32; off; off >>= 1) s += __shfl_xor(s, off);
    __shared__ float reds[4];
    if ((t & 63) == 0) reds[t >> 6] = s;
    __syncthreads();
    s = reds[0] + reds[1] + reds[2] + reds[3];
    const float inv = 1.0f / s;

    _Float16* prow = (_Float16*)srow;
    half8 o0, o1;
#pragma unroll
    for (int j = 0; j < 8; ++j) {
        o0[j] = (_Float16)(x[j] * inv);
        o1[j] = (_Float16)(x[8 + j] * inv);
    }
    __syncthreads();
    *(half8*)(prow + t * 16)     = o0;
    *(half8*)(prow + t * 16 + 8) = o1;
}

// ---------------------------------------------------------------------------
extern "C" void kernel_launch(void* const* d_in, const int* in_sizes, int n_in,
                              void* d_out, int out_size, void* d_ws, size_t ws_size,
                              hipStream_t stream) {
    const float* x1 = (const float*)d_in[0];
    const float* x2 = (const float*)d_in[1];
    const float* Wq = (const float*)d_in[2];
    const float* Wk = (const float*)d_in[3];
    const float* Wv = (const float*)d_in[4];
    float* out = (float*)d_out;

    const int NQ = 4096, NKV = 4096, D = 1024;

    // workspace (MB).  S (0..64) overlays buffers dead before the S GEMM.
    char* ws = (char*)d_ws;
    float*    S      = (float*)ws;                       //   0..64
    _Float16* x1cat  = (_Float16*)(ws);                  //   0..24  [4096][3072] A-style (dead after T)
    _Float16* Wqcat  = (_Float16*)(ws + (24u  << 20));   //  24..30  [1024][3072] B-style (dead after Mt)
    _Float16* Wkcat  = (_Float16*)(ws + (30u  << 20));   //  30..36  [1024][3072] A-style (dead after Mt)
    _Float16* Mtcat  = (_Float16*)(ws + (36u  << 20));   //  36..42  [1024][3072] B-style (dead after T)
    _Float16* Wvct   = (_Float16*)(ws + (42u  << 20));   //  42..48  [1024][3072] B-style (dead after V)
    _Float16* x2cat  = (_Float16*)(ws + (64u  << 20));   //  64..88  [4096][3072] B-style (live thru S)
    _Float16* Tcat   = (_Float16*)(ws + (88u  << 20));   //  88..112 [4096][3072] A-style (live thru S)
    _Float16* Vt     = (_Float16*)(ws + (112u << 20));   // 112..120 [1024][4096] f16 (live thru PV)

    // 1) casts: x1 -> A-style, x2 -> B-style; Wk -> A-style, Wq -> B-style;
    //    Wv -> transposed B-style (hi segment used at K=1024)
    split_cast_pair<<<(2 * NQ * D) / 1024, 256, 0, stream>>>(
        x1, x1cat, x2, x2cat, D, NQ * D);
    split_cast_pair<<<(2 * D * D) / 1024, 256, 0, stream>>>(
        Wk, Wkcat, Wq, Wqcat, D, D * D);
    dim3 tb(32, 8), tg(D / 32, D / 32);
    transpose_split_b<<<tg, tb, 0, stream>>>(Wv, Wvct, D);

    // 2) M^T = Wk @ Wq^T  (split-3 in, B-style split out), 8-wave kernel
    gemm_bt8<5><<<dim3(D / 128, D / 128), 512, 0, stream>>>(
        Wkcat, Wqcat, Mtcat, D, D, 3 * D, 3 * D, 3 * D, 1.0f);

    // 3) T = x1 @ M  (A-style split out) -- replaces BOTH Q and K projections
    gemm_bt8<4><<<dim3(D / 128, NQ / 128), 512, 0, stream>>>(
        x1cat, Mtcat, Tcat, NQ, D, 3 * D, 3 * D, 3 * D, 1.0f);

    // 4) V^T: plain f16, K=1024 (hi segments)
    gemm_bt8<1><<<dim3(D / 128, NKV / 128), 512, 0, stream>>>(
        x2cat, Wvct, Vt, NKV, D, D, 3 * D, 3 * D, 1.0f);

    // 5) scores: S = (T @ x2^T)/32 = (Q K^T)/32, K=3072, pipelined 256^2
    gemm256_bt_f32<<<dim3(NKV / 256, NQ / 256), 512, 0, stream>>>(
        Tcat, x2cat, S, NQ, NKV, 3 * D, 3 * D, 3 * D, 1.0f / 32.0f);

    // 6) softmax rows in place: f32 scores -> normalized f16 P (stride 8192 f16)
    softmax_inplace<<<NQ, 256, 0, stream>>>(S, NKV);

    // 7) out = P @ V  (A = P f16, lda=8192; B^T = Vt[D][NKV], ldb=4096)
    gemm_bt8<3><<<dim3(D / 128, NQ / 128), 512, 0, stream>>>(
        (const _Float16*)S, Vt, out, NQ, D, NKV, 2 * NKV, NKV, 1.0f);
}

// Round 14
// 317.646 us; speedup vs baseline: 1.0316x; 1.0316x over previous
//
#include <hip/hip_runtime.h>
#include <hip/hip_fp16.h>
#include <stdint.h>

typedef _Float16 half8 __attribute__((ext_vector_type(8)));
typedef _Float16 half4v __attribute__((ext_vector_type(4)));
typedef float floatx4 __attribute__((ext_vector_type(4)));

// ---------------------------------------------------------------------------
// async global->LDS copy, 16B per lane. LDS dest = wave-uniform base + lane*16.
__device__ inline void gload_lds16(const void* g, void* l) {
    __builtin_amdgcn_global_load_lds(
        (const __attribute__((address_space(1))) uint32_t*)g,
        (__attribute__((address_space(3))) uint32_t*)l, 16, 0, 0);
}

// ---------------------------------------------------------------------------
// Fused split-cast for all four flat inputs:
//   region 0: x1 -> A-style [hi|lo|hi] at x1cat   (n1 elems, width nc)
//   region 1: x2 -> B-style [hi|hi|lo] at x2cat   (n1)
//   region 2: Wk -> A-style at Wkcat              (n2)
//   region 3: Wq -> B-style at Wqcat              (n2)
__global__ __launch_bounds__(256) void split_cast_all(
    const float* __restrict__ x1, _Float16* __restrict__ x1cat,
    const float* __restrict__ x2, _Float16* __restrict__ x2cat,
    const float* __restrict__ Wk, _Float16* __restrict__ Wkcat,
    const float* __restrict__ Wq, _Float16* __restrict__ Wqcat,
    int nc, int n1, int n2) {
    int i = (blockIdx.x * 256 + threadIdx.x) * 4;
    const float* src;
    _Float16* out;
    bool astyle;
    if (i < 2 * n1) {
        astyle = (i < n1);
        const int ii = astyle ? i : i - n1;
        src = (astyle ? x1 : x2) + ii;
        out = astyle ? x1cat : x2cat;
        i = ii;
    } else {
        int j = i - 2 * n1;
        if (j >= 2 * n2) return;
        astyle = (j < n2);
        const int ii = astyle ? j : j - n2;
        src = (astyle ? Wk : Wq) + ii;
        out = astyle ? Wkcat : Wqcat;
        i = ii;
    }
    float4 v = *(const float4*)src;
    int r = i / nc, c = i % nc;
    half4v hi, lo;
    hi[0] = (_Float16)v.x; lo[0] = (_Float16)(v.x - (float)hi[0]);
    hi[1] = (_Float16)v.y; lo[1] = (_Float16)(v.y - (float)hi[1]);
    hi[2] = (_Float16)v.z; lo[2] = (_Float16)(v.z - (float)hi[2]);
    hi[3] = (_Float16)v.w; lo[3] = (_Float16)(v.w - (float)hi[3]);
    size_t base = (size_t)r * 3 * nc;
    if (astyle) {   // [hi|lo|hi]
        *(half4v*)(out + base + c) = hi;
        *(half4v*)(out + base + nc + c) = lo;
        *(half4v*)(out + base + 2 * nc + c) = hi;
    } else {        // [hi|hi|lo]
        *(half4v*)(out + base + c) = hi;
        *(half4v*)(out + base + nc + c) = hi;
        *(half4v*)(out + base + 2 * nc + c) = lo;
    }
}

// ---------------------------------------------------------------------------
// transpose + B-style split cat [hi | hi | lo]: out[n][...]=f(in[k][n]).
__global__ __launch_bounds__(256) void transpose_split_b(
    const float* __restrict__ in, _Float16* __restrict__ out, int dim) {
    __shared__ float tile[32][33];
    const int tx = threadIdx.x, ty = threadIdx.y;
    const int bx = blockIdx.x * 32, by = blockIdx.y * 32;
#pragma unroll
    for (int i = 0; i < 32; i += 8)
        tile[ty + i][tx] = in[(size_t)(by + ty + i) * dim + bx + tx];
    __syncthreads();
#pragma unroll
    for (int i = 0; i < 32; i += 8) {
        float v = tile[tx][ty + i];
        _Float16 hi = (_Float16)v;
        _Float16 lo = (_Float16)(v - (float)hi);
        size_t o = (size_t)(bx + ty + i) * 3 * dim + by + tx;
        out[o] = hi;
        out[o + dim] = hi;
        out[o + 2 * dim] = lo;
    }
}

// ---------------------------------------------------------------------------
// 128x128-tile, 512-thread / 8-wave (4M x 2N) GEMM: C = A @ B^T.
// Each wave owns a 32x64 sub-tile (acc 2x4) -> 2 waves/SIMD overlap.
template <int OMODE>
__global__ __launch_bounds__(512) void gemm_bt8(
    const _Float16* __restrict__ A, const _Float16* __restrict__ B,
    void* __restrict__ Cout, int M, int N, int K, int lda, int ldb,
    float cscale) {
    __shared__ _Float16 As[128 * 64];
    __shared__ _Float16 Bs[128 * 64];

    const int tid  = threadIdx.x;
    const int lane = tid & 63;
    const int wid  = tid >> 6;    // 0..7
    const int wr   = wid >> 1;    // 0..3  M-quarter (32 rows)
    const int wc   = wid & 1;     // 0..1  N-half (64 cols)
    const int row0 = blockIdx.y * 128;
    const int col0 = blockIdx.x * 128;

    floatx4 acc[2][4] = {};

    const int srow   = lane >> 3;
    const int schunk = (lane & 7) ^ srow;      // source-side XOR swizzle
    const char* gA = (const char*)(A + (size_t)(row0 + wid * 8 + srow) * lda) + schunk * 16;
    const char* gB = (const char*)(B + (size_t)(col0 + wid * 8 + srow) * ldb) + schunk * 16;
    char* lA = (char*)As + (wid * 8) * 128;
    char* lB = (char*)Bs + (wid * 8) * 128;

    const int frow   = lane & 15;
    const int rxor   = frow & 7;
    const int kchunk = lane >> 4;

    const int kTiles = K >> 6;
    for (int kt = 0; kt < kTiles; ++kt) {
        const size_t kb = (size_t)(kt << 6) * 2;
#pragma unroll
        for (int r = 0; r < 2; ++r) {
            gload_lds16(gA + (size_t)(r * 64) * lda * 2 + kb, lA + r * 64 * 128);
            gload_lds16(gB + (size_t)(r * 64) * ldb * 2 + kb, lB + r * 64 * 128);
        }
        __syncthreads();
#pragma unroll
        for (int kk = 0; kk < 2; ++kk) {
            half8 af[2], bf[4];
            const int pc = ((kk * 4 + kchunk) ^ rxor) * 16;
#pragma unroll
            for (int mi = 0; mi < 2; ++mi)
                af[mi] = *(const half8*)((const char*)As + (wr * 32 + mi * 16 + frow) * 128 + pc);
#pragma unroll
            for (int ni = 0; ni < 4; ++ni)
                bf[ni] = *(const half8*)((const char*)Bs + (wc * 64 + ni * 16 + frow) * 128 + pc);
#pragma unroll
            for (int mi = 0; mi < 2; ++mi)
#pragma unroll
                for (int ni = 0; ni < 4; ++ni)
                    acc[mi][ni] = __builtin_amdgcn_mfma_f32_16x16x32_f16(
                        af[mi], bf[ni], acc[mi][ni], 0, 0, 0);
        }
        __syncthreads();
    }

    // epilogue: D row = 4*(lane>>4)+j, col = lane&15
    const int orow0 = row0 + wr * 32 + ((lane >> 4) << 2);
    const int ocol0 = col0 + wc * 64 + (lane & 15);
#pragma unroll
    for (int mi = 0; mi < 2; ++mi) {
#pragma unroll
        for (int ni = 0; ni < 4; ++ni) {
#pragma unroll
            for (int j = 0; j < 4; ++j) {
                const int rr = orow0 + mi * 16 + j;
                const int cc = ocol0 + ni * 16;
                const float v = acc[mi][ni][j] * cscale;
                if (OMODE == 1) {
                    ((_Float16*)Cout)[(size_t)cc * M + rr] = (_Float16)v;
                } else if (OMODE == 3) {
                    ((float*)Cout)[(size_t)rr * N + cc] = v;
                } else {
                    _Float16 hi = (_Float16)v;
                    _Float16 lo = (_Float16)(v - (float)hi);
                    _Float16* o = (_Float16*)Cout + (size_t)rr * 3 * N + cc;
                    if (OMODE == 4) { o[0] = hi; o[N] = lo; o[2 * N] = hi; }
                    else            { o[0] = hi; o[N] = hi; o[2 * N] = lo; }
                }
            }
        }
    }
}

// ---------------------------------------------------------------------------
// 256x256-tile, BK=64, 8-wave (2Mx4N), 4 phases/K-tile with PER-PHASE spread
// staging + counted vmcnt(6).  (R12-verified: 108.6 us, VGPR 104, MfmaUtil 38.)
// Dead-region schedule: P3 stages tile t+2's B + A-MH0 into buf[cur] (last
// readers P2, published by its closing barrier); next-P0 stages t+2's A-MH1
// (dead after P3's closing barrier).  vmcnt(6) drains exactly tile t+1.
#define SB0() __builtin_amdgcn_sched_barrier(0)
#define BAR() __builtin_amdgcn_s_barrier()

#define PH_READS(KK, MH, DO_B)                                                \
    {                                                                         \
        const int pc_ = (((KK) * 4 + kchunk) ^ rxor) * 16;                    \
        if (DO_B) {                                                           \
            _Pragma("unroll")                                                 \
            for (int ni = 0; ni < 4; ++ni)                                    \
                bf[ni] = *(const half8*)(bsB + (wc * 64 + ni * 16 + frow) * 128 + pc_); \
        }                                                                     \
        _Pragma("unroll")                                                     \
        for (int mi = 0; mi < 4; ++mi)                                        \
            af[mi] = *(const half8*)(bsA + (wr * 128 + ((MH) * 4 + mi) * 16 + frow) * 128 + pc_); \
    }

#define PH_MFMA(MH)                                                           \
    __builtin_amdgcn_s_setprio(1);                                            \
    _Pragma("unroll")                                                         \
    for (int mi = 0; mi < 4; ++mi)                                            \
        _Pragma("unroll")                                                     \
        for (int ni = 0; ni < 4; ++ni)                                        \
            acc[(MH) * 4 + mi][ni] = __builtin_amdgcn_mfma_f32_16x16x32_f16(  \
                af[mi], bf[ni], acc[(MH) * 4 + mi][ni], 0, 0, 0);             \
    __builtin_amdgcn_s_setprio(0);

#define STG_A(DST, tt, i)                                                     \
    gload_lds16(gA + (size_t)((i) * 64) * lda + (size_t)(tt) * 64,            \
                (char*)(DST) + (wid * 8 + (i) * 64) * 128);
#define STG_B(DST, tt, i)                                                     \
    gload_lds16(gB + (size_t)((i) * 64) * ldb + (size_t)(tt) * 64,            \
                (char*)(DST) + (wid * 8 + (i) * 64) * 128);

__global__ __launch_bounds__(512, 2) void gemm256_bt_f32(
    const _Float16* __restrict__ A, const _Float16* __restrict__ B,
    float* __restrict__ C, int M, int N, int K, int lda, int ldb,
    float cscale) {
    __shared__ _Float16 As[2][256 * 64];   // 2 x 32 KiB
    __shared__ _Float16 Bs[2][256 * 64];   // 2 x 32 KiB  (total 128 KiB)

    const int tid  = threadIdx.x;
    const int lane = tid & 63;
    const int wid  = tid >> 6;     // 0..7
    const int wr   = wid >> 2;     // 0..1  M-half
    const int wc   = wid & 3;      // 0..3  N-quarter
    const int row0 = blockIdx.y * 256;
    const int col0 = blockIdx.x * 256;

    floatx4 acc[8][4] = {};

    const int srow   = lane >> 3;
    const int schunk = (lane & 7) ^ srow;    // pre-swizzled global source
    const _Float16* gA = A + (size_t)(row0 + wid * 8 + srow) * lda + schunk * 8;
    const _Float16* gB = B + (size_t)(col0 + wid * 8 + srow) * ldb + schunk * 8;

    const int frow   = lane & 15;
    const int rxor   = frow & 7;
    const int kchunk = lane >> 4;

    const int NT = K >> 6;

    // prologue: stage tiles 0 and 1 fully; wait tile 0 (tile 1's 8 in flight)
#pragma unroll
    for (int i = 0; i < 4; ++i) { STG_A((char*)As[0], 0, i) STG_B((char*)Bs[0], 0, i) }
#pragma unroll
    for (int i = 0; i < 4; ++i) { STG_A((char*)As[1], 1, i) STG_B((char*)Bs[1], 1, i) }
    asm volatile("s_waitcnt vmcnt(8)" ::: "memory");
    SB0();
    BAR();

    half8 af[4], bf[4];
    for (int t = 0; t < NT; ++t) {
        const int d = t & 1;
        char* curA = (char*)As[0] + d * 32768;
        char* curB = (char*)Bs[0] + d * 32768;
        char* nxtA = (char*)As[0] + (d ^ 1) * 32768;
        const char* bsA = curA;
        const char* bsB = curB;

        // ---- P0: kk0, MH0 (+B kk0); then finish staging tile t+1 (A-MH1)
        PH_READS(0, 0, true)
        if (t >= 1 && t + 1 < NT) { STG_A(nxtA, t + 1, 1) STG_A(nxtA, t + 1, 3) }
        SB0();
        BAR();
        asm volatile("s_waitcnt lgkmcnt(0)" ::: "memory");
        SB0();
        PH_MFMA(0)
        BAR();

        // ---- P1: kk0, MH1
        PH_READS(0, 1, false)
        SB0();
        BAR();
        asm volatile("s_waitcnt lgkmcnt(0)" ::: "memory");
        SB0();
        PH_MFMA(1)
        BAR();

        // ---- P2: kk1, MH0 (+B kk1)
        PH_READS(1, 0, true)
        SB0();
        BAR();
        asm volatile("s_waitcnt lgkmcnt(0)" ::: "memory");
        SB0();
        PH_MFMA(0)
        BAR();

        // ---- P3: kk1, MH1; stage 6 of tile t+2 into dead regions of cur
        PH_READS(1, 1, false)
        const bool pf = (t + 2 < NT);
        if (pf) {
            STG_B(curB, t + 2, 0) STG_B(curB, t + 2, 1)
            STG_B(curB, t + 2, 2) STG_B(curB, t + 2, 3)
            STG_A(curA, t + 2, 0) STG_A(curA, t + 2, 2)
        }
        SB0();
        BAR();
        asm volatile("s_waitcnt lgkmcnt(0)" ::: "memory");
        SB0();
        if (pf) { asm volatile("s_waitcnt vmcnt(6)" ::: "memory"); }
        else    { asm volatile("s_waitcnt vmcnt(0)" ::: "memory"); }
        SB0();
        PH_MFMA(1)
        BAR();   // tile t+1 resident; its A-MH1 region (cur) now dead
    }

    // epilogue: D row = 4*(lane>>4)+j, col = lane&15
    const int orow0 = row0 + wr * 128 + ((lane >> 4) << 2);
    const int ocol0 = col0 + wc * 64 + frow;
#pragma unroll
    for (int mi = 0; mi < 8; ++mi) {
#pragma unroll
        for (int ni = 0; ni < 4; ++ni) {
#pragma unroll
            for (int j = 0; j < 4; ++j) {
                const int rr = orow0 + mi * 16 + j;
                const int cc = ocol0 + ni * 16;
                C[(size_t)rr * N + cc] = acc[mi][ni][j] * cscale;
            }
        }
    }
}

// ---------------------------------------------------------------------------
// row softmax over f32 S (already scaled /32), in place: writes normalized
// P = exp(s-m)/sum as f16 at the same row base (row stride ncols f32 slots).
__global__ __launch_bounds__(256) void softmax_inplace(
    float* __restrict__ S, int ncols) {
    const int row = blockIdx.x;
    float* srow = S + (size_t)row * ncols;
    const int t = threadIdx.x;

    float x[16];
#pragma unroll
    for (int q = 0; q < 4; ++q) {
        float4 v = *(float4*)(srow + t * 16 + q * 4);
        x[q * 4 + 0] = v.x; x[q * 4 + 1] = v.y;
        x[q * 4 + 2] = v.z; x[q * 4 + 3] = v.w;
    }
    float m = x[0];
#pragma unroll
    for (int j = 1; j < 16; ++j) m = fmaxf(m, x[j]);
#pragma unroll
    for (int off = 32; off; off >>= 1) m = fmaxf(m, __shfl_xor(m, off));
    __shared__ float redm[4];
    if ((t & 63) == 0) redm[t >> 6] = m;
    __syncthreads();
    m = fmaxf(fmaxf(redm[0], redm[1]), fmaxf(redm[2], redm[3]));

    float s = 0.0f;
#pragma unroll
    for (int j = 0; j < 16; ++j) {
        x[j] = __expf(x[j] - m);
        s += x[j];
    }
#pragma unroll
    for (int off = 32; off; off >>= 1) s += __shfl_xor(s, off);
    __shared__ float reds[4];
    if ((t & 63) == 0) reds[t >> 6] = s;
    __syncthreads();
    s = reds[0] + reds[1] + reds[2] + reds[3];
    const float inv = 1.0f / s;

    _Float16* prow = (_Float16*)srow;
    half8 o0, o1;
#pragma unroll
    for (int j = 0; j < 8; ++j) {
        o0[j] = (_Float16)(x[j] * inv);
        o1[j] = (_Float16)(x[8 + j] * inv);
    }
    __syncthreads();
    *(half8*)(prow + t * 16)     = o0;
    *(half8*)(prow + t * 16 + 8) = o1;
}

// ---------------------------------------------------------------------------
extern "C" void kernel_launch(void* const* d_in, const int* in_sizes, int n_in,
                              void* d_out, int out_size, void* d_ws, size_t ws_size,
                              hipStream_t stream) {
    const float* x1 = (const float*)d_in[0];
    const float* x2 = (const float*)d_in[1];
    const float* Wq = (const float*)d_in[2];
    const float* Wk = (const float*)d_in[3];
    const float* Wv = (const float*)d_in[4];
    float* out = (float*)d_out;

    const int NQ = 4096, NKV = 4096, D = 1024;

    // workspace (MB).  S (0..64) overlays buffers dead before the S GEMM.
    char* ws = (char*)d_ws;
    float*    S      = (float*)ws;                       //   0..64
    _Float16* x1cat  = (_Float16*)(ws);                  //   0..24  [4096][3072] A-style (dead after T)
    _Float16* Wqcat  = (_Float16*)(ws + (24u  << 20));   //  24..30  [1024][3072] B-style (dead after Mt)
    _Float16* Wkcat  = (_Float16*)(ws + (30u  << 20));   //  30..36  [1024][3072] A-style (dead after Mt)
    _Float16* Mtcat  = (_Float16*)(ws + (36u  << 20));   //  36..42  [1024][3072] B-style (dead after T)
    _Float16* Wvct   = (_Float16*)(ws + (42u  << 20));   //  42..48  [1024][3072] B-style (dead after V)
    _Float16* x2cat  = (_Float16*)(ws + (64u  << 20));   //  64..88  [4096][3072] B-style (live thru S)
    _Float16* Tcat   = (_Float16*)(ws + (88u  << 20));   //  88..112 [4096][3072] A-style (live thru S)
    _Float16* Vt     = (_Float16*)(ws + (112u << 20));   // 112..120 [1024][4096] f16 (live thru PV)

    // 1) fused casts: x1->A, x2->B, Wk->A, Wq->B; Wv -> transposed B-style
    const int n1 = NQ * D, n2 = D * D;
    split_cast_all<<<(2 * (n1 + n2) + 1023) / 1024, 256, 0, stream>>>(
        x1, x1cat, x2, x2cat, Wk, Wkcat, Wq, Wqcat, D, n1, n2);
    dim3 tb(32, 8), tg(D / 32, D / 32);
    transpose_split_b<<<tg, tb, 0, stream>>>(Wv, Wvct, D);

    // 2) M^T = Wk @ Wq^T  (split-3 in, B-style split out), 8-wave kernel
    gemm_bt8<5><<<dim3(D / 128, D / 128), 512, 0, stream>>>(
        Wkcat, Wqcat, Mtcat, D, D, 3 * D, 3 * D, 3 * D, 1.0f);

    // 3) T = x1 @ M  (A-style split out) -- replaces BOTH Q and K projections
    gemm_bt8<4><<<dim3(D / 128, NQ / 128), 512, 0, stream>>>(
        x1cat, Mtcat, Tcat, NQ, D, 3 * D, 3 * D, 3 * D, 1.0f);

    // 4) V^T: plain f16, K=1024 (hi segments)
    gemm_bt8<1><<<dim3(D / 128, NKV / 128), 512, 0, stream>>>(
        x2cat, Wvct, Vt, NKV, D, D, 3 * D, 3 * D, 1.0f);

    // 5) scores: S = (T @ x2^T)/32 = (Q K^T)/32, K=3072, spread-staging 256^2
    gemm256_bt_f32<<<dim3(NKV / 256, NQ / 256), 512, 0, stream>>>(
        Tcat, x2cat, S, NQ, NKV, 3 * D, 3 * D, 3 * D, 1.0f / 32.0f);

    // 6) softmax rows in place: f32 scores -> normalized f16 P (stride 8192 f16)
    softmax_inplace<<<NQ, 256, 0, stream>>>(S, NKV);

    // 7) out = P @ V  (A = P f16, lda=8192; B^T = Vt[D][NKV], ldb=4096)
    gemm_bt8<3><<<dim3(D / 128, NQ / 128), 512, 0, stream>>>(
        (const _Float16*)S, Vt, out, NQ, D, NKV, 2 * NKV, NKV, 1.0f);
}

// Round 15
// 316.816 us; speedup vs baseline: 1.0343x; 1.0026x over previous
//
#include <hip/hip_runtime.h>
#include <hip/hip_fp16.h>
#include <stdint.h>

typedef _Float16 half8 __attribute__((ext_vector_type(8)));
typedef _Float16 half4v __attribute__((ext_vector_type(4)));
typedef float floatx4 __attribute__((ext_vector_type(4)));

// ---------------------------------------------------------------------------
// async global->LDS copy, 16B per lane. LDS dest = wave-uniform base + lane*16.
__device__ inline void gload_lds16(const void* g, void* l) {
    __builtin_amdgcn_global_load_lds(
        (const __attribute__((address_space(1))) uint32_t*)g,
        (__attribute__((address_space(3))) uint32_t*)l, 16, 0, 0);
}

// ---------------------------------------------------------------------------
// Fused split-cast for all four flat inputs:
//   region 0: x1 -> A-style [hi|lo|hi] at x1cat   (n1 elems, width nc)
//   region 1: x2 -> B-style [hi|hi|lo] at x2cat   (n1)
//   region 2: Wk -> A-style at Wkcat              (n2)
//   region 3: Wq -> B-style at Wqcat              (n2)
__global__ __launch_bounds__(256) void split_cast_all(
    const float* __restrict__ x1, _Float16* __restrict__ x1cat,
    const float* __restrict__ x2, _Float16* __restrict__ x2cat,
    const float* __restrict__ Wk, _Float16* __restrict__ Wkcat,
    const float* __restrict__ Wq, _Float16* __restrict__ Wqcat,
    int nc, int n1, int n2) {
    int i = (blockIdx.x * 256 + threadIdx.x) * 4;
    const float* src;
    _Float16* out;
    bool astyle;
    if (i < 2 * n1) {
        astyle = (i < n1);
        const int ii = astyle ? i : i - n1;
        src = (astyle ? x1 : x2) + ii;
        out = astyle ? x1cat : x2cat;
        i = ii;
    } else {
        int j = i - 2 * n1;
        if (j >= 2 * n2) return;
        astyle = (j < n2);
        const int ii = astyle ? j : j - n2;
        src = (astyle ? Wk : Wq) + ii;
        out = astyle ? Wkcat : Wqcat;
        i = ii;
    }
    float4 v = *(const float4*)src;
    int r = i / nc, c = i % nc;
    half4v hi, lo;
    hi[0] = (_Float16)v.x; lo[0] = (_Float16)(v.x - (float)hi[0]);
    hi[1] = (_Float16)v.y; lo[1] = (_Float16)(v.y - (float)hi[1]);
    hi[2] = (_Float16)v.z; lo[2] = (_Float16)(v.z - (float)hi[2]);
    hi[3] = (_Float16)v.w; lo[3] = (_Float16)(v.w - (float)hi[3]);
    size_t base = (size_t)r * 3 * nc;
    if (astyle) {   // [hi|lo|hi]
        *(half4v*)(out + base + c) = hi;
        *(half4v*)(out + base + nc + c) = lo;
        *(half4v*)(out + base + 2 * nc + c) = hi;
    } else {        // [hi|hi|lo]
        *(half4v*)(out + base + c) = hi;
        *(half4v*)(out + base + nc + c) = hi;
        *(half4v*)(out + base + 2 * nc + c) = lo;
    }
}

// ---------------------------------------------------------------------------
// transpose + B-style split cat [hi | hi | lo]: out[n][...]=f(in[k][n]).
__global__ __launch_bounds__(256) void transpose_split_b(
    const float* __restrict__ in, _Float16* __restrict__ out, int dim) {
    __shared__ float tile[32][33];
    const int tx = threadIdx.x, ty = threadIdx.y;
    const int bx = blockIdx.x * 32, by = blockIdx.y * 32;
#pragma unroll
    for (int i = 0; i < 32; i += 8)
        tile[ty + i][tx] = in[(size_t)(by + ty + i) * dim + bx + tx];
    __syncthreads();
#pragma unroll
    for (int i = 0; i < 32; i += 8) {
        float v = tile[tx][ty + i];
        _Float16 hi = (_Float16)v;
        _Float16 lo = (_Float16)(v - (float)hi);
        size_t o = (size_t)(bx + ty + i) * 3 * dim + by + tx;
        out[o] = hi;
        out[o + dim] = hi;
        out[o + 2 * dim] = lo;
    }
}

// ---------------------------------------------------------------------------
// 128x128-tile, 512-thread / 8-wave (4M x 2N) GEMM: C = A @ B^T.
// Each wave owns a 32x64 sub-tile (acc 2x4) -> 2 waves/SIMD overlap.
template <int OMODE>
__global__ __launch_bounds__(512) void gemm_bt8(
    const _Float16* __restrict__ A, const _Float16* __restrict__ B,
    void* __restrict__ Cout, int M, int N, int K, int lda, int ldb,
    float cscale) {
    __shared__ _Float16 As[128 * 64];
    __shared__ _Float16 Bs[128 * 64];

    const int tid  = threadIdx.x;
    const int lane = tid & 63;
    const int wid  = tid >> 6;    // 0..7
    const int wr   = wid >> 1;    // 0..3  M-quarter (32 rows)
    const int wc   = wid & 1;     // 0..1  N-half (64 cols)
    const int row0 = blockIdx.y * 128;
    const int col0 = blockIdx.x * 128;

    floatx4 acc[2][4] = {};

    const int srow   = lane >> 3;
    const int schunk = (lane & 7) ^ srow;      // source-side XOR swizzle
    const char* gA = (const char*)(A + (size_t)(row0 + wid * 8 + srow) * lda) + schunk * 16;
    const char* gB = (const char*)(B + (size_t)(col0 + wid * 8 + srow) * ldb) + schunk * 16;
    char* lA = (char*)As + (wid * 8) * 128;
    char* lB = (char*)Bs + (wid * 8) * 128;

    const int frow   = lane & 15;
    const int rxor   = frow & 7;
    const int kchunk = lane >> 4;

    const int kTiles = K >> 6;
    for (int kt = 0; kt < kTiles; ++kt) {
        const size_t kb = (size_t)(kt << 6) * 2;
#pragma unroll
        for (int r = 0; r < 2; ++r) {
            gload_lds16(gA + (size_t)(r * 64) * lda * 2 + kb, lA + r * 64 * 128);
            gload_lds16(gB + (size_t)(r * 64) * ldb * 2 + kb, lB + r * 64 * 128);
        }
        __syncthreads();
#pragma unroll
        for (int kk = 0; kk < 2; ++kk) {
            half8 af[2], bf[4];
            const int pc = ((kk * 4 + kchunk) ^ rxor) * 16;
#pragma unroll
            for (int mi = 0; mi < 2; ++mi)
                af[mi] = *(const half8*)((const char*)As + (wr * 32 + mi * 16 + frow) * 128 + pc);
#pragma unroll
            for (int ni = 0; ni < 4; ++ni)
                bf[ni] = *(const half8*)((const char*)Bs + (wc * 64 + ni * 16 + frow) * 128 + pc);
#pragma unroll
            for (int mi = 0; mi < 2; ++mi)
#pragma unroll
                for (int ni = 0; ni < 4; ++ni)
                    acc[mi][ni] = __builtin_amdgcn_mfma_f32_16x16x32_f16(
                        af[mi], bf[ni], acc[mi][ni], 0, 0, 0);
        }
        __syncthreads();
    }

    // epilogue: D row = 4*(lane>>4)+j, col = lane&15
    const int orow0 = row0 + wr * 32 + ((lane >> 4) << 2);
    const int ocol0 = col0 + wc * 64 + (lane & 15);
#pragma unroll
    for (int mi = 0; mi < 2; ++mi) {
#pragma unroll
        for (int ni = 0; ni < 4; ++ni) {
#pragma unroll
            for (int j = 0; j < 4; ++j) {
                const int rr = orow0 + mi * 16 + j;
                const int cc = ocol0 + ni * 16;
                const float v = acc[mi][ni][j] * cscale;
                if (OMODE == 1) {
                    ((_Float16*)Cout)[(size_t)cc * M + rr] = (_Float16)v;
                } else if (OMODE == 3) {
                    ((float*)Cout)[(size_t)rr * N + cc] = v;
                } else {
                    _Float16 hi = (_Float16)v;
                    _Float16 lo = (_Float16)(v - (float)hi);
                    _Float16* o = (_Float16*)Cout + (size_t)rr * 3 * N + cc;
                    if (OMODE == 4) { o[0] = hi; o[N] = lo; o[2 * N] = hi; }
                    else            { o[0] = hi; o[N] = hi; o[2 * N] = lo; }
                }
            }
        }
    }
}

// ---------------------------------------------------------------------------
// 256x256-tile, BK=64, 8-wave (2Mx4N), 4 phases/K-tile.  B split into per-kk
// half-buffers (B0/B1, 64B rows) so staging spreads 2/2/0/4 (vs R12's 2/0/0/6):
//   B0(t) dead after P0 (frags reg-reused in P1) -> P1 stages B0(t+2);
//   B1(t), A-MH0(t) dead after P2 -> P3 stages B1(t+2)+A-MH0(t+2);
//   A-MH1(t) dead after P3 -> next-P0 stages A-MH1(t+1) into nxt dbuf.
// Ledger: single vmcnt(6) at P3 leaves exactly {B0,B1,A-MH0}(t+2) = 6 loads
// flying and guarantees tile t+1 fully resident.  Prologue vmcnt(8).
// B0/B1 bank swizzle: read pchunk = kchunk ^ ((frow>>1)&3) (conflict-free per
// 8-lane service group); staging source pre-swizzled (lane&3)^((lane>>3)&3),
// LDS dest linear base+lane*16 (both-sides rule).
#define SB0() __builtin_amdgcn_sched_barrier(0)
#define BAR() __builtin_amdgcn_s_barrier()

#define RD_A4(KK, MH)                                                         \
    {                                                                         \
        const int pc_ = (((KK) * 4 + kchunk) ^ rxor) * 16;                    \
        _Pragma("unroll")                                                     \
        for (int mi = 0; mi < 4; ++mi)                                        \
            af[mi] = *(const half8*)(bsA + (wr * 128 + ((MH) * 4 + mi) * 16 + frow) * 128 + pc_); \
    }

#define RD_B4(BUF)                                                            \
    {                                                                         \
        _Pragma("unroll")                                                     \
        for (int ni = 0; ni < 4; ++ni)                                        \
            bf[ni] = *(const half8*)((BUF) + (wc * 64 + ni * 16 + frow) * 64 + bco); \
    }

#define PH_MFMA(MH)                                                           \
    __builtin_amdgcn_s_setprio(1);                                            \
    _Pragma("unroll")                                                         \
    for (int mi = 0; mi < 4; ++mi)                                            \
        _Pragma("unroll")                                                     \
        for (int ni = 0; ni < 4; ++ni)                                        \
            acc[(MH) * 4 + mi][ni] = __builtin_amdgcn_mfma_f32_16x16x32_f16(  \
                af[mi], bf[ni], acc[(MH) * 4 + mi][ni], 0, 0, 0);             \
    __builtin_amdgcn_s_setprio(0);

#define STG_A(DST, tt, i)                                                     \
    gload_lds16(gA + (size_t)((i) * 64) * lda + (size_t)(tt) * 64,            \
                (char*)(DST) + (wid * 8 + (i) * 64) * 128);
// B half-buffer staging: instr i covers rows wid*16 + i*128 + (lane>>2),
// 64B rows; source K offset = tt*64 + HALF*32 + pre-swizzled chunk.
#define STG_B2(DST, tt, HALF, i)                                              \
    gload_lds16(gB2 + (size_t)((i) * 128) * ldb + (size_t)(tt) * 64 + (HALF) * 32, \
                (char*)(DST) + (wid * 16 + (i) * 128) * 64);

__global__ __launch_bounds__(512, 2) void gemm256_bt_f32(
    const _Float16* __restrict__ A, const _Float16* __restrict__ B,
    float* __restrict__ C, int M, int N, int K, int lda, int ldb,
    float cscale) {
    __shared__ _Float16 As[2][256 * 64];    // 2 x 32 KiB
    __shared__ _Float16 Bs0[2][256 * 32];   // 2 x 16 KiB (kk0 half)
    __shared__ _Float16 Bs1[2][256 * 32];   // 2 x 16 KiB (kk1 half) -> 128 KiB

    const int tid  = threadIdx.x;
    const int lane = tid & 63;
    const int wid  = tid >> 6;     // 0..7
    const int wr   = wid >> 2;     // 0..1  M-half
    const int wc   = wid & 3;      // 0..3  N-quarter
    const int row0 = blockIdx.y * 256;
    const int col0 = blockIdx.x * 256;

    floatx4 acc[8][4] = {};

    // A staging (128B rows, chunk-XOR swizzle)
    const int srow   = lane >> 3;
    const int schunk = (lane & 7) ^ srow;
    const _Float16* gA = A + (size_t)(row0 + wid * 8 + srow) * lda + schunk * 8;
    // B staging (64B rows): row = wid*16 + i*128 + (lane>>2),
    // source chunk = (lane&3)^((lane>>3)&3), 8 f16 each
    const _Float16* gB2 = B + (size_t)(col0 + wid * 16 + (lane >> 2)) * ldb
                            + ((lane & 3) ^ ((lane >> 3) & 3)) * 8;

    const int frow   = lane & 15;
    const int rxor   = frow & 7;
    const int kchunk = lane >> 4;
    const int bco    = (kchunk ^ ((frow >> 1) & 3)) * 16;   // B read chunk byte

    const int NT = K >> 6;

    // prologue: stage tiles 0 and 1 fully; wait tile 0 (tile 1's 8 in flight)
#pragma unroll
    for (int i = 0; i < 4; ++i) { STG_A((char*)As[0], 0, i) }
#pragma unroll
    for (int i = 0; i < 2; ++i) { STG_B2((char*)Bs0[0], 0, 0, i) STG_B2((char*)Bs1[0], 0, 1, i) }
#pragma unroll
    for (int i = 0; i < 4; ++i) { STG_A((char*)As[1], 1, i) }
#pragma unroll
    for (int i = 0; i < 2; ++i) { STG_B2((char*)Bs0[1], 1, 0, i) STG_B2((char*)Bs1[1], 1, 1, i) }
    asm volatile("s_waitcnt vmcnt(8)" ::: "memory");
    SB0();
    BAR();

    half8 af[4], bf[4];
    for (int t = 0; t < NT; ++t) {
        const int d = t & 1;
        char* curA  = (char*)As[0]  + d * 32768;
        char* nxtA  = (char*)As[0]  + (d ^ 1) * 32768;
        char* curB0 = (char*)Bs0[0] + d * 16384;
        char* curB1 = (char*)Bs1[0] + d * 16384;
        const char* bsA = curA;
        const bool pf = (t + 2 < NT);

        // ---- P0: A(kk0,MH0) + B0; finish staging tile t+1's A-MH1 into nxt
        RD_A4(0, 0)
        RD_B4(curB0)
        if (t >= 1 && t + 1 < NT) { STG_A(nxtA, t + 1, 1) STG_A(nxtA, t + 1, 3) }
        SB0();
        BAR();
        asm volatile("s_waitcnt lgkmcnt(0)" ::: "memory");
        SB0();
        PH_MFMA(0)
        BAR();                      // B0(t) now dead (frags held in regs)

        // ---- P1: A(kk0,MH1), B0 frags reused; stage B0(t+2) into curB0
        RD_A4(0, 1)
        if (pf) { STG_B2(curB0, t + 2, 0, 0) STG_B2(curB0, t + 2, 0, 1) }
        SB0();
        BAR();
        asm volatile("s_waitcnt lgkmcnt(0)" ::: "memory");
        SB0();
        PH_MFMA(1)
        BAR();

        // ---- P2: A(kk1,MH0) + B1
        RD_A4(1, 0)
        RD_B4(curB1)
        SB0();
        BAR();
        asm volatile("s_waitcnt lgkmcnt(0)" ::: "memory");
        SB0();
        PH_MFMA(0)
        BAR();                      // B1(t), A-MH0(t) now dead

        // ---- P3: A(kk1,MH1), B1 reused; stage B1(t+2)+A-MH0(t+2); vmcnt(6)
        RD_A4(1, 1)
        if (pf) {
            STG_B2(curB1, t + 2, 1, 0) STG_B2(curB1, t + 2, 1, 1)
            STG_A(curA, t + 2, 0) STG_A(curA, t + 2, 2)
        }
        SB0();
        BAR();
        asm volatile("s_waitcnt lgkmcnt(0)" ::: "memory");
        SB0();
        if (pf) { asm volatile("s_waitcnt vmcnt(6)" ::: "memory"); }
        else    { asm volatile("s_waitcnt vmcnt(0)" ::: "memory"); }
        SB0();
        PH_MFMA(1)
        BAR();                      // tile t+1 resident; A-MH1(t) now dead
    }

    // epilogue: D row = 4*(lane>>4)+j, col = lane&15
    const int orow0 = row0 + wr * 128 + ((lane >> 4) << 2);
    const int ocol0 = col0 + wc * 64 + frow;
#pragma unroll
    for (int mi = 0; mi < 8; ++mi) {
#pragma unroll
        for (int ni = 0; ni < 4; ++ni) {
#pragma unroll
            for (int j = 0; j < 4; ++j) {
                const int rr = orow0 + mi * 16 + j;
                const int cc = ocol0 + ni * 16;
                C[(size_t)rr * N + cc] = acc[mi][ni][j] * cscale;
            }
        }
    }
}

// ---------------------------------------------------------------------------
// row softmax over f32 S (already scaled /32), in place: writes normalized
// P = exp(s-m)/sum as f16 at the same row base (row stride ncols f32 slots).
__global__ __launch_bounds__(256) void softmax_inplace(
    float* __restrict__ S, int ncols) {
    const int row = blockIdx.x;
    float* srow = S + (size_t)row * ncols;
    const int t = threadIdx.x;

    float x[16];
#pragma unroll
    for (int q = 0; q < 4; ++q) {
        float4 v = *(float4*)(srow + t * 16 + q * 4);
        x[q * 4 + 0] = v.x; x[q * 4 + 1] = v.y;
        x[q * 4 + 2] = v.z; x[q * 4 + 3] = v.w;
    }
    float m = x[0];
#pragma unroll
    for (int j = 1; j < 16; ++j) m = fmaxf(m, x[j]);
#pragma unroll
    for (int off = 32; off; off >>= 1) m = fmaxf(m, __shfl_xor(m, off));
    __shared__ float redm[4];
    if ((t & 63) == 0) redm[t >> 6] = m;
    __syncthreads();
    m = fmaxf(fmaxf(redm[0], redm[1]), fmaxf(redm[2], redm[3]));

    float s = 0.0f;
#pragma unroll
    for (int j = 0; j < 16; ++j) {
        x[j] = __expf(x[j] - m);
        s += x[j];
    }
#pragma unroll
    for (int off = 32; off; off >>= 1) s += __shfl_xor(s, off);
    __shared__ float reds[4];
    if ((t & 63) == 0) reds[t >> 6] = s;
    __syncthreads();
    s = reds[0] + reds[1] + reds[2] + reds[3];
    const float inv = 1.0f / s;

    _Float16* prow = (_Float16*)srow;
    half8 o0, o1;
#pragma unroll
    for (int j = 0; j < 8; ++j) {
        o0[j] = (_Float16)(x[j] * inv);
        o1[j] = (_Float16)(x[8 + j] * inv);
    }
    __syncthreads();
    *(half8*)(prow + t * 16)     = o0;
    *(half8*)(prow + t * 16 + 8) = o1;
}

// ---------------------------------------------------------------------------
extern "C" void kernel_launch(void* const* d_in, const int* in_sizes, int n_in,
                              void* d_out, int out_size, void* d_ws, size_t ws_size,
                              hipStream_t stream) {
    const float* x1 = (const float*)d_in[0];
    const float* x2 = (const float*)d_in[1];
    const float* Wq = (const float*)d_in[2];
    const float* Wk = (const float*)d_in[3];
    const float* Wv = (const float*)d_in[4];
    float* out = (float*)d_out;

    const int NQ = 4096, NKV = 4096, D = 1024;

    // workspace (MB).  S (0..64) overlays buffers dead before the S GEMM.
    char* ws = (char*)d_ws;
    float*    S      = (float*)ws;                       //   0..64
    _Float16* x1cat  = (_Float16*)(ws);                  //   0..24  [4096][3072] A-style (dead after T)
    _Float16* Wqcat  = (_Float16*)(ws + (24u  << 20));   //  24..30  [1024][3072] B-style (dead after Mt)
    _Float16* Wkcat  = (_Float16*)(ws + (30u  << 20));   //  30..36  [1024][3072] A-style (dead after Mt)
    _Float16* Mtcat  = (_Float16*)(ws + (36u  << 20));   //  36..42  [1024][3072] B-style (dead after T)
    _Float16* Wvct   = (_Float16*)(ws + (42u  << 20));   //  42..48  [1024][3072] B-style (dead after V)
    _Float16* x2cat  = (_Float16*)(ws + (64u  << 20));   //  64..88  [4096][3072] B-style (live thru S)
    _Float16* Tcat   = (_Float16*)(ws + (88u  << 20));   //  88..112 [4096][3072] A-style (live thru S)
    _Float16* Vt     = (_Float16*)(ws + (112u << 20));   // 112..120 [1024][4096] f16 (live thru PV)

    // 1) fused casts: x1->A, x2->B, Wk->A, Wq->B; Wv -> transposed B-style
    const int n1 = NQ * D, n2 = D * D;
    split_cast_all<<<(2 * (n1 + n2) + 1023) / 1024, 256, 0, stream>>>(
        x1, x1cat, x2, x2cat, Wk, Wkcat, Wq, Wqcat, D, n1, n2);
    dim3 tb(32, 8), tg(D / 32, D / 32);
    transpose_split_b<<<tg, tb, 0, stream>>>(Wv, Wvct, D);

    // 2) M^T = Wk @ Wq^T  (split-3 in, B-style split out), 8-wave kernel
    gemm_bt8<5><<<dim3(D / 128, D / 128), 512, 0, stream>>>(
        Wkcat, Wqcat, Mtcat, D, D, 3 * D, 3 * D, 3 * D, 1.0f);

    // 3) T = x1 @ M  (A-style split out) -- replaces BOTH Q and K projections
    gemm_bt8<4><<<dim3(D / 128, NQ / 128), 512, 0, stream>>>(
        x1cat, Mtcat, Tcat, NQ, D, 3 * D, 3 * D, 3 * D, 1.0f);

    // 4) V^T: plain f16, K=1024 (hi segments)
    gemm_bt8<1><<<dim3(D / 128, NKV / 128), 512, 0, stream>>>(
        x2cat, Wvct, Vt, NKV, D, D, 3 * D, 3 * D, 1.0f);

    // 5) scores: S = (T @ x2^T)/32 = (Q K^T)/32, K=3072, split-B 256^2 kernel
    gemm256_bt_f32<<<dim3(NKV / 256, NQ / 256), 512, 0, stream>>>(
        Tcat, x2cat, S, NQ, NKV, 3 * D, 3 * D, 3 * D, 1.0f / 32.0f);

    // 6) softmax rows in place: f32 scores -> normalized f16 P (stride 8192 f16)
    softmax_inplace<<<NQ, 256, 0, stream>>>(S, NKV);

    // 7) out = P @ V  (A = P f16, lda=8192; B^T = Vt[D][NKV], ldb=4096)
    gemm_bt8<3><<<dim3(D / 128, NQ / 128), 512, 0, stream>>>(
        (const _Float16*)S, Vt, out, NQ, D, NKV, 2 * NKV, NKV, 1.0f);
}

// Round 16
// 308.402 us; speedup vs baseline: 1.0625x; 1.0273x over previous
//
#include <hip/hip_runtime.h>
#include <hip/hip_fp16.h>
#include <stdint.h>

typedef _Float16 half8 __attribute__((ext_vector_type(8)));
typedef _Float16 half4v __attribute__((ext_vector_type(4)));
typedef float floatx4 __attribute__((ext_vector_type(4)));

// ---------------------------------------------------------------------------
// async global->LDS copy, 16B per lane. LDS dest = wave-uniform base + lane*16.
__device__ inline void gload_lds16(const void* g, void* l) {
    __builtin_amdgcn_global_load_lds(
        (const __attribute__((address_space(1))) uint32_t*)g,
        (__attribute__((address_space(3))) uint32_t*)l, 16, 0, 0);
}

// ---------------------------------------------------------------------------
// XCD-aware chunked block swizzle (T1, m157): hardware dispatches flat block
// id w to XCD w%8; remap so XCD k owns a CONTIGUOUS chunk of tile-space ->
// same-row tiles share one L2 (A-panel fetched once per XCD, not 8x).
// Requires nwg % 8 == 0 (all grids here: 64 or 256).  Bijective.
__device__ inline void xcd_swizzle(int nx, int& bx, int& by) {
    const int nwg  = nx * gridDim.y;
    const int orig = by * nx + bx;
    const int cpx  = nwg >> 3;                  // chunk per XCD
    const int t    = (orig & 7) * cpx + (orig >> 3);
    bx = t % nx;
    by = t / nx;
}

// ---------------------------------------------------------------------------
// Fused split-cast for all four flat inputs:
//   region 0: x1 -> A-style [hi|lo|hi] at x1cat   (n1 elems, width nc)
//   region 1: x2 -> B-style [hi|hi|lo] at x2cat   (n1)
//   region 2: Wk -> A-style at Wkcat              (n2)
//   region 3: Wq -> B-style at Wqcat              (n2)
__global__ __launch_bounds__(256) void split_cast_all(
    const float* __restrict__ x1, _Float16* __restrict__ x1cat,
    const float* __restrict__ x2, _Float16* __restrict__ x2cat,
    const float* __restrict__ Wk, _Float16* __restrict__ Wkcat,
    const float* __restrict__ Wq, _Float16* __restrict__ Wqcat,
    int nc, int n1, int n2) {
    int i = (blockIdx.x * 256 + threadIdx.x) * 4;
    const float* src;
    _Float16* out;
    bool astyle;
    if (i < 2 * n1) {
        astyle = (i < n1);
        const int ii = astyle ? i : i - n1;
        src = (astyle ? x1 : x2) + ii;
        out = astyle ? x1cat : x2cat;
        i = ii;
    } else {
        int j = i - 2 * n1;
        if (j >= 2 * n2) return;
        astyle = (j < n2);
        const int ii = astyle ? j : j - n2;
        src = (astyle ? Wk : Wq) + ii;
        out = astyle ? Wkcat : Wqcat;
        i = ii;
    }
    float4 v = *(const float4*)src;
    int r = i / nc, c = i % nc;
    half4v hi, lo;
    hi[0] = (_Float16)v.x; lo[0] = (_Float16)(v.x - (float)hi[0]);
    hi[1] = (_Float16)v.y; lo[1] = (_Float16)(v.y - (float)hi[1]);
    hi[2] = (_Float16)v.z; lo[2] = (_Float16)(v.z - (float)hi[2]);
    hi[3] = (_Float16)v.w; lo[3] = (_Float16)(v.w - (float)hi[3]);
    size_t base = (size_t)r * 3 * nc;
    if (astyle) {   // [hi|lo|hi]
        *(half4v*)(out + base + c) = hi;
        *(half4v*)(out + base + nc + c) = lo;
        *(half4v*)(out + base + 2 * nc + c) = hi;
    } else {        // [hi|hi|lo]
        *(half4v*)(out + base + c) = hi;
        *(half4v*)(out + base + nc + c) = hi;
        *(half4v*)(out + base + 2 * nc + c) = lo;
    }
}

// ---------------------------------------------------------------------------
// transpose + B-style split cat [hi | hi | lo]: out[n][...]=f(in[k][n]).
__global__ __launch_bounds__(256) void transpose_split_b(
    const float* __restrict__ in, _Float16* __restrict__ out, int dim) {
    __shared__ float tile[32][33];
    const int tx = threadIdx.x, ty = threadIdx.y;
    const int bx = blockIdx.x * 32, by = blockIdx.y * 32;
#pragma unroll
    for (int i = 0; i < 32; i += 8)
        tile[ty + i][tx] = in[(size_t)(by + ty + i) * dim + bx + tx];
    __syncthreads();
#pragma unroll
    for (int i = 0; i < 32; i += 8) {
        float v = tile[tx][ty + i];
        _Float16 hi = (_Float16)v;
        _Float16 lo = (_Float16)(v - (float)hi);
        size_t o = (size_t)(bx + ty + i) * 3 * dim + by + tx;
        out[o] = hi;
        out[o + dim] = hi;
        out[o + 2 * dim] = lo;
    }
}

// ---------------------------------------------------------------------------
// 128x128-tile, 512-thread / 8-wave (4M x 2N) GEMM: C = A @ B^T.
// Each wave owns a 32x64 sub-tile (acc 2x4) -> 2 waves/SIMD overlap.
template <int OMODE>
__global__ __launch_bounds__(512) void gemm_bt8(
    const _Float16* __restrict__ A, const _Float16* __restrict__ B,
    void* __restrict__ Cout, int M, int N, int K, int lda, int ldb,
    float cscale) {
    __shared__ _Float16 As[128 * 64];
    __shared__ _Float16 Bs[128 * 64];

    const int tid  = threadIdx.x;
    const int lane = tid & 63;
    const int wid  = tid >> 6;    // 0..7
    const int wr   = wid >> 1;    // 0..3  M-quarter (32 rows)
    const int wc   = wid & 1;     // 0..1  N-half (64 cols)
    int bx = blockIdx.x, by = blockIdx.y;
    xcd_swizzle(gridDim.x, bx, by);
    const int row0 = by * 128;
    const int col0 = bx * 128;

    floatx4 acc[2][4] = {};

    const int srow   = lane >> 3;
    const int schunk = (lane & 7) ^ srow;      // source-side XOR swizzle
    const char* gA = (const char*)(A + (size_t)(row0 + wid * 8 + srow) * lda) + schunk * 16;
    const char* gB = (const char*)(B + (size_t)(col0 + wid * 8 + srow) * ldb) + schunk * 16;
    char* lA = (char*)As + (wid * 8) * 128;
    char* lB = (char*)Bs + (wid * 8) * 128;

    const int frow   = lane & 15;
    const int rxor   = frow & 7;
    const int kchunk = lane >> 4;

    const int kTiles = K >> 6;
    for (int kt = 0; kt < kTiles; ++kt) {
        const size_t kb = (size_t)(kt << 6) * 2;
#pragma unroll
        for (int r = 0; r < 2; ++r) {
            gload_lds16(gA + (size_t)(r * 64) * lda * 2 + kb, lA + r * 64 * 128);
            gload_lds16(gB + (size_t)(r * 64) * ldb * 2 + kb, lB + r * 64 * 128);
        }
        __syncthreads();
#pragma unroll
        for (int kk = 0; kk < 2; ++kk) {
            half8 af[2], bf[4];
            const int pc = ((kk * 4 + kchunk) ^ rxor) * 16;
#pragma unroll
            for (int mi = 0; mi < 2; ++mi)
                af[mi] = *(const half8*)((const char*)As + (wr * 32 + mi * 16 + frow) * 128 + pc);
#pragma unroll
            for (int ni = 0; ni < 4; ++ni)
                bf[ni] = *(const half8*)((const char*)Bs + (wc * 64 + ni * 16 + frow) * 128 + pc);
#pragma unroll
            for (int mi = 0; mi < 2; ++mi)
#pragma unroll
                for (int ni = 0; ni < 4; ++ni)
                    acc[mi][ni] = __builtin_amdgcn_mfma_f32_16x16x32_f16(
                        af[mi], bf[ni], acc[mi][ni], 0, 0, 0);
        }
        __syncthreads();
    }

    // epilogue: D row = 4*(lane>>4)+j, col = lane&15
    const int orow0 = row0 + wr * 32 + ((lane >> 4) << 2);
    const int ocol0 = col0 + wc * 64 + (lane & 15);
#pragma unroll
    for (int mi = 0; mi < 2; ++mi) {
#pragma unroll
        for (int ni = 0; ni < 4; ++ni) {
#pragma unroll
            for (int j = 0; j < 4; ++j) {
                const int rr = orow0 + mi * 16 + j;
                const int cc = ocol0 + ni * 16;
                const float v = acc[mi][ni][j] * cscale;
                if (OMODE == 1) {
                    ((_Float16*)Cout)[(size_t)cc * M + rr] = (_Float16)v;
                } else if (OMODE == 3) {
                    ((float*)Cout)[(size_t)rr * N + cc] = v;
                } else {
                    _Float16 hi = (_Float16)v;
                    _Float16 lo = (_Float16)(v - (float)hi);
                    _Float16* o = (_Float16*)Cout + (size_t)rr * 3 * N + cc;
                    if (OMODE == 4) { o[0] = hi; o[N] = lo; o[2 * N] = hi; }
                    else            { o[0] = hi; o[N] = hi; o[2 * N] = lo; }
                }
            }
        }
    }
}

// ---------------------------------------------------------------------------
// 256x256-tile, BK=64, 8-wave (2Mx4N), 4 phases/K-tile with PER-PHASE spread
// staging + counted vmcnt(6).  (R12-verified: 108.5 us, VGPR 104, MfmaUtil 38.)
#define SB0() __builtin_amdgcn_sched_barrier(0)
#define BAR() __builtin_amdgcn_s_barrier()

#define PH_READS(KK, MH, DO_B)                                                \
    {                                                                         \
        const int pc_ = (((KK) * 4 + kchunk) ^ rxor) * 16;                    \
        if (DO_B) {                                                           \
            _Pragma("unroll")                                                 \
            for (int ni = 0; ni < 4; ++ni)                                    \
                bf[ni] = *(const half8*)(bsB + (wc * 64 + ni * 16 + frow) * 128 + pc_); \
        }                                                                     \
        _Pragma("unroll")                                                     \
        for (int mi = 0; mi < 4; ++mi)                                        \
            af[mi] = *(const half8*)(bsA + (wr * 128 + ((MH) * 4 + mi) * 16 + frow) * 128 + pc_); \
    }

#define PH_MFMA(MH)                                                           \
    __builtin_amdgcn_s_setprio(1);                                            \
    _Pragma("unroll")                                                         \
    for (int mi = 0; mi < 4; ++mi)                                            \
        _Pragma("unroll")                                                     \
        for (int ni = 0; ni < 4; ++ni)                                        \
            acc[(MH) * 4 + mi][ni] = __builtin_amdgcn_mfma_f32_16x16x32_f16(  \
                af[mi], bf[ni], acc[(MH) * 4 + mi][ni], 0, 0, 0);             \
    __builtin_amdgcn_s_setprio(0);

#define STG_A(DST, tt, i)                                                     \
    gload_lds16(gA + (size_t)((i) * 64) * lda + (size_t)(tt) * 64,            \
                (char*)(DST) + (wid * 8 + (i) * 64) * 128);
#define STG_B(DST, tt, i)                                                     \
    gload_lds16(gB + (size_t)((i) * 64) * ldb + (size_t)(tt) * 64,            \
                (char*)(DST) + (wid * 8 + (i) * 64) * 128);

__global__ __launch_bounds__(512, 2) void gemm256_bt_f32(
    const _Float16* __restrict__ A, const _Float16* __restrict__ B,
    float* __restrict__ C, int M, int N, int K, int lda, int ldb,
    float cscale) {
    __shared__ _Float16 As[2][256 * 64];   // 2 x 32 KiB
    __shared__ _Float16 Bs[2][256 * 64];   // 2 x 32 KiB  (total 128 KiB)

    const int tid  = threadIdx.x;
    const int lane = tid & 63;
    const int wid  = tid >> 6;     // 0..7
    const int wr   = wid >> 2;     // 0..1  M-half
    const int wc   = wid & 3;      // 0..3  N-quarter
    int bx = blockIdx.x, by = blockIdx.y;
    xcd_swizzle(gridDim.x, bx, by);
    const int row0 = by * 256;
    const int col0 = bx * 256;

    floatx4 acc[8][4] = {};

    const int srow   = lane >> 3;
    const int schunk = (lane & 7) ^ srow;    // pre-swizzled global source
    const _Float16* gA = A + (size_t)(row0 + wid * 8 + srow) * lda + schunk * 8;
    const _Float16* gB = B + (size_t)(col0 + wid * 8 + srow) * ldb + schunk * 8;

    const int frow   = lane & 15;
    const int rxor   = frow & 7;
    const int kchunk = lane >> 4;

    const int NT = K >> 6;

    // prologue: stage tiles 0 and 1 fully; wait tile 0 (tile 1's 8 in flight)
#pragma unroll
    for (int i = 0; i < 4; ++i) { STG_A((char*)As[0], 0, i) STG_B((char*)Bs[0], 0, i) }
#pragma unroll
    for (int i = 0; i < 4; ++i) { STG_A((char*)As[1], 1, i) STG_B((char*)Bs[1], 1, i) }
    asm volatile("s_waitcnt vmcnt(8)" ::: "memory");
    SB0();
    BAR();

    half8 af[4], bf[4];
    for (int t = 0; t < NT; ++t) {
        const int d = t & 1;
        char* curA = (char*)As[0] + d * 32768;
        char* curB = (char*)Bs[0] + d * 32768;
        char* nxtA = (char*)As[0] + (d ^ 1) * 32768;
        const char* bsA = curA;
        const char* bsB = curB;

        // ---- P0: kk0, MH0 (+B kk0); then finish staging tile t+1 (A-MH1)
        PH_READS(0, 0, true)
        if (t >= 1 && t + 1 < NT) { STG_A(nxtA, t + 1, 1) STG_A(nxtA, t + 1, 3) }
        SB0();
        BAR();
        asm volatile("s_waitcnt lgkmcnt(0)" ::: "memory");
        SB0();
        PH_MFMA(0)
        BAR();

        // ---- P1: kk0, MH1
        PH_READS(0, 1, false)
        SB0();
        BAR();
        asm volatile("s_waitcnt lgkmcnt(0)" ::: "memory");
        SB0();
        PH_MFMA(1)
        BAR();

        // ---- P2: kk1, MH0 (+B kk1)
        PH_READS(1, 0, true)
        SB0();
        BAR();
        asm volatile("s_waitcnt lgkmcnt(0)" ::: "memory");
        SB0();
        PH_MFMA(0)
        BAR();

        // ---- P3: kk1, MH1; stage 6 of tile t+2 into dead regions of cur
        PH_READS(1, 1, false)
        const bool pf = (t + 2 < NT);
        if (pf) {
            STG_B(curB, t + 2, 0) STG_B(curB, t + 2, 1)
            STG_B(curB, t + 2, 2) STG_B(curB, t + 2, 3)
            STG_A(curA, t + 2, 0) STG_A(curA, t + 2, 2)
        }
        SB0();
        BAR();
        asm volatile("s_waitcnt lgkmcnt(0)" ::: "memory");
        SB0();
        if (pf) { asm volatile("s_waitcnt vmcnt(6)" ::: "memory"); }
        else    { asm volatile("s_waitcnt vmcnt(0)" ::: "memory"); }
        SB0();
        PH_MFMA(1)
        BAR();   // tile t+1 resident; its A-MH1 region (cur) now dead
    }

    // epilogue: D row = 4*(lane>>4)+j, col = lane&15
    const int orow0 = row0 + wr * 128 + ((lane >> 4) << 2);
    const int ocol0 = col0 + wc * 64 + frow;
#pragma unroll
    for (int mi = 0; mi < 8; ++mi) {
#pragma unroll
        for (int ni = 0; ni < 4; ++ni) {
#pragma unroll
            for (int j = 0; j < 4; ++j) {
                const int rr = orow0 + mi * 16 + j;
                const int cc = ocol0 + ni * 16;
                C[(size_t)rr * N + cc] = acc[mi][ni][j] * cscale;
            }
        }
    }
}

// ---------------------------------------------------------------------------
// row softmax over f32 S (already scaled /32), in place: writes normalized
// P = exp(s-m)/sum as f16 at the same row base (row stride ncols f32 slots).
__global__ __launch_bounds__(256) void softmax_inplace(
    float* __restrict__ S, int ncols) {
    const int row = blockIdx.x;
    float* srow = S + (size_t)row * ncols;
    const int t = threadIdx.x;

    float x[16];
#pragma unroll
    for (int q = 0; q < 4; ++q) {
        float4 v = *(float4*)(srow + t * 16 + q * 4);
        x[q * 4 + 0] = v.x; x[q * 4 + 1] = v.y;
        x[q * 4 + 2] = v.z; x[q * 4 + 3] = v.w;
    }
    float m = x[0];
#pragma unroll
    for (int j = 1; j < 16; ++j) m = fmaxf(m, x[j]);
#pragma unroll
    for (int off = 32; off; off >>= 1) m = fmaxf(m, __shfl_xor(m, off));
    __shared__ float redm[4];
    if ((t & 63) == 0) redm[t >> 6] = m;
    __syncthreads();
    m = fmaxf(fmaxf(redm[0], redm[1]), fmaxf(redm[2], redm[3]));

    float s = 0.0f;
#pragma unroll
    for (int j = 0; j < 16; ++j) {
        x[j] = __expf(x[j] - m);
        s += x[j];
    }
#pragma unroll
    for (int off = 32; off; off >>= 1) s += __shfl_xor(s, off);
    __shared__ float reds[4];
    if ((t & 63) == 0) reds[t >> 6] = s;
    __syncthreads();
    s = reds[0] + reds[1] + reds[2] + reds[3];
    const float inv = 1.0f / s;

    _Float16* prow = (_Float16*)srow;
    half8 o0, o1;
#pragma unroll
    for (int j = 0; j < 8; ++j) {
        o0[j] = (_Float16)(x[j] * inv);
        o1[j] = (_Float16)(x[8 + j] * inv);
    }
    __syncthreads();
    *(half8*)(prow + t * 16)     = o0;
    *(half8*)(prow + t * 16 + 8) = o1;
}

// ---------------------------------------------------------------------------
extern "C" void kernel_launch(void* const* d_in, const int* in_sizes, int n_in,
                              void* d_out, int out_size, void* d_ws, size_t ws_size,
                              hipStream_t stream) {
    const float* x1 = (const float*)d_in[0];
    const float* x2 = (const float*)d_in[1];
    const float* Wq = (const float*)d_in[2];
    const float* Wk = (const float*)d_in[3];
    const float* Wv = (const float*)d_in[4];
    float* out = (float*)d_out;

    const int NQ = 4096, NKV = 4096, D = 1024;

    // workspace (MB).  S (0..64) overlays buffers dead before the S GEMM.
    char* ws = (char*)d_ws;
    float*    S      = (float*)ws;                       //   0..64
    _Float16* x1cat  = (_Float16*)(ws);                  //   0..24  [4096][3072] A-style (dead after T)
    _Float16* Wqcat  = (_Float16*)(ws + (24u  << 20));   //  24..30  [1024][3072] B-style (dead after Mt)
    _Float16* Wkcat  = (_Float16*)(ws + (30u  << 20));   //  30..36  [1024][3072] A-style (dead after Mt)
    _Float16* Mtcat  = (_Float16*)(ws + (36u  << 20));   //  36..42  [1024][3072] B-style (dead after T)
    _Float16* Wvct   = (_Float16*)(ws + (42u  << 20));   //  42..48  [1024][3072] B-style (dead after V)
    _Float16* x2cat  = (_Float16*)(ws + (64u  << 20));   //  64..88  [4096][3072] B-style (live thru S)
    _Float16* Tcat   = (_Float16*)(ws + (88u  << 20));   //  88..112 [4096][3072] A-style (live thru S)
    _Float16* Vt     = (_Float16*)(ws + (112u << 20));   // 112..120 [1024][4096] f16 (live thru PV)

    // 1) fused casts: x1->A, x2->B, Wk->A, Wq->B; Wv -> transposed B-style
    const int n1 = NQ * D, n2 = D * D;
    split_cast_all<<<(2 * (n1 + n2) + 1023) / 1024, 256, 0, stream>>>(
        x1, x1cat, x2, x2cat, Wk, Wkcat, Wq, Wqcat, D, n1, n2);
    dim3 tb(32, 8), tg(D / 32, D / 32);
    transpose_split_b<<<tg, tb, 0, stream>>>(Wv, Wvct, D);

    // 2) M^T = Wk @ Wq^T  (split-3 in, B-style split out), 8-wave kernel
    gemm_bt8<5><<<dim3(D / 128, D / 128), 512, 0, stream>>>(
        Wkcat, Wqcat, Mtcat, D, D, 3 * D, 3 * D, 3 * D, 1.0f);

    // 3) T = x1 @ M  (A-style split out) -- replaces BOTH Q and K projections
    gemm_bt8<4><<<dim3(D / 128, NQ / 128), 512, 0, stream>>>(
        x1cat, Mtcat, Tcat, NQ, D, 3 * D, 3 * D, 3 * D, 1.0f);

    // 4) V^T: plain f16, K=1024 (hi segments)
    gemm_bt8<1><<<dim3(D / 128, NKV / 128), 512, 0, stream>>>(
        x2cat, Wvct, Vt, NKV, D, D, 3 * D, 3 * D, 1.0f);

    // 5) scores: S = (T @ x2^T)/32 = (Q K^T)/32, K=3072, spread-staging 256^2
    gemm256_bt_f32<<<dim3(NKV / 256, NQ / 256), 512, 0, stream>>>(
        Tcat, x2cat, S, NQ, NKV, 3 * D, 3 * D, 3 * D, 1.0f / 32.0f);

    // 6) softmax rows in place: f32 scores -> normalized f16 P (stride 8192 f16)
    softmax_inplace<<<NQ, 256, 0, stream>>>(S, NKV);

    // 7) out = P @ V  (A = P f16, lda=8192; B^T = Vt[D][NKV], ldb=4096)
    gemm_bt8<3><<<dim3(D / 128, NQ / 128), 512, 0, stream>>>(
        (const _Float16*)S, Vt, out, NQ, D, NKV, 2 * NKV, NKV, 1.0f);
}